// Round 5
// baseline (1555.149 us; speedup 1.0000x reference)
//
#include <hip/hip_runtime.h>
#include <math.h>

#define NFFT 1024
#define BLK  512   // two batches per block: waves 0-3 = batch A, 4-7 = batch B

// quad_perm DPP (VALU pipe). 0xB1 = lane^1, 0x4E = lane^2, 0x1B = lane^3.
template <int CTRL>
__device__ __forceinline__ float dppf(float v) {
    return __int_as_float(__builtin_amdgcn_update_dpp(
        0, __float_as_int(v), CTRL, 0xF, 0xF, true));
}

__global__ __launch_bounds__(BLK)
void siva_kernel(const float* __restrict__ x,
                 const float* __restrict__ nu_p,
                 const float* __restrict__ dto_p,
                 const float* __restrict__ cr_p,
                 const int* __restrict__ nt_p,
                 const int* __restrict__ ns_p,
                 float* __restrict__ out) {
    __shared__ float2 bufT[2 * NFFT];    // forward transpose (per sub-batch slab)
    __shared__ float2 bufT2[2 * NFFT];   // inverse transpose

    const int t  = threadIdx.x;
    const int sl = t >> 8;              // sub-batch slot 0/1
    const int tt = t & 255;             // within-batch thread
    const int b  = blockIdx.x * 2 + sl; // global batch
    const int sb = sl * NFFT;           // LDS slab base
    const int l  = t & 63;
    const int w  = tt >> 6;
    // radix-4 digit reversal of lane: l = 16a+4b2+c -> R = a + 4*b2 + 16*c
    const int R = (l >> 4) | (l & 12) | ((l & 3) << 4);

    const int nT   = nt_p[0];
    const int nsub = ns_p[0];

    const float nu  = (1.0f / (1.0f + expf(-nu_p[0])))  * (0.5f - 0.01f)  + 0.01f;
    const float dto = (1.0f / (1.0f + expf(-dto_p[0]))) * (0.1f - 0.001f) + 0.001f;
    const float cR  = (1.0f / (1.0f + expf(-cr_p[0])))  * (2.0f - 0.5f)   + 0.5f;
    const float dt   = dto / (float)nsub;
    const float dtcR = dt * cR;

    // Stage A twiddles W1024^{tt*r}; Stage B twiddles W256^{l*r}
    float2 TA[3], TB[3];
    #pragma unroll
    for (int r = 1; r <= 3; ++r) {
        const float a = (float)(tt * r) * (1.0f / 512.0f);   // pi units
        TA[r - 1] = make_float2(cospif(a), -sinpif(a));
        const float a2 = (float)(l * r) * (1.0f / 128.0f);
        TB[r - 1] = make_float2(cospif(a2), -sinpif(a2));
    }

    // Lane-FFT radix-4 per-stage per-lane weights (as Round 4, verified).
    float2 GF[3][4], GI[3][4];
    {
        const int hs[3] = {16, 4, 1};
        #pragma unroll
        for (int s = 0; s < 3; ++s) {
            const int h = hs[s];
            const int a = (l / h) & 3;
            const int m = l % h;
            const float invM = 1.0f / (float)(4 * h);
            #pragma unroll
            for (int d = 0; d < 4; ++d) {
                const int e4 = ((d ^ a) * a) & 3;
                const float angF = 0.5f * (float)e4
                                 + 2.0f * (float)(a * m) * invM;      // pi units
                GF[s][d] = make_float2(cospif(angF), -sinpif(angF));
                const float angI = 0.5f * (float)e4
                                 + 2.0f * (float)((d ^ a) * m) * invM;
                GI[2 - s][d] = make_float2(cospif(angI), sinpif(angI));
            }
        }
    }

    // Spectral constants. k = 16*R + 4*r2 + w.
    float Sc[4], csn[4], si[4];
    #pragma unroll
    for (int r2 = 0; r2 < 4; ++r2) {
        const int k = 16 * R + 4 * r2 + w;
        const float kk = (k <= 512) ? (float)k : (float)(k - 1024);
        const float ka = fabsf(kk);
        const float q  = 1.0f - dtcR * (ka - nu * ka * ka);
        const float a  = (1.0f / q) * (1.0f / 1024.0f);
        const float kkS = (k == 0 || k == 512) ? 0.0f : kk;
        Sc[r2]  = a * (1.0f - dt * kkS);
        csn[r2] = (k == 0) ? 0.0f : (1.0f / (1024.0f * kk));
        si[r2]  = kk * (1.0f / 1024.0f);
    }

    // Fused quad operator: C[r2][e] = sum_d GI0[d] * S_{l^d}[r2] * GF2_{l^d}[d^e]
    // (replaces fwd h=1 stage + spectral scale + inv h=1 stage).
    float2 Cf[4][4];
    #pragma unroll
    for (int r2 = 0; r2 < 4; ++r2) {
        #pragma unroll
        for (int e = 0; e < 4; ++e) {
            float cx = 0.0f, cy = 0.0f;
            #pragma unroll
            for (int d = 0; d < 4; ++d) {
                const float sd = __shfl_xor(Sc[r2], d);
                const float gx = __shfl_xor(GF[2][d ^ e].x, d);
                const float gy = __shfl_xor(GF[2][d ^ e].y, d);
                const float2 gi = GI[0][d];
                // cx+icy += sd * (gi * g)
                cx = fmaf(sd, gi.x * gx - gi.y * gy, cx);
                cy = fmaf(sd, gi.x * gy + gi.y * gx, cy);
            }
            Cf[r2][e] = make_float2(cx, cy);
        }
    }

    auto radix4f = [](float2& z0, float2& z1, float2& z2, float2& z3,
                      const float2 T1, const float2 T2, const float2 T3) {
        const float2 apc = make_float2(z0.x + z2.x, z0.y + z2.y);
        const float2 amc = make_float2(z0.x - z2.x, z0.y - z2.y);
        const float2 bpd = make_float2(z1.x + z3.x, z1.y + z3.y);
        const float2 bmd = make_float2(z1.x - z3.x, z1.y - z3.y);
        const float2 y0 = make_float2(apc.x + bpd.x, apc.y + bpd.y);
        const float2 y1 = make_float2(amc.x + bmd.y, amc.y - bmd.x);
        const float2 y2 = make_float2(apc.x - bpd.x, apc.y - bpd.y);
        const float2 y3 = make_float2(amc.x - bmd.y, amc.y + bmd.x);
        z0 = y0;
        z1 = make_float2(y1.x * T1.x - y1.y * T1.y, y1.x * T1.y + y1.y * T1.x);
        z2 = make_float2(y2.x * T2.x - y2.y * T2.y, y2.x * T2.y + y2.y * T2.x);
        z3 = make_float2(y3.x * T3.x - y3.y * T3.y, y3.x * T3.y + y3.y * T3.x);
    };

    // y = g0*z0 + g1*z1 + g2*z2 + g3*z3 (complex)
    auto c4 = [](float2 g0, float2 z0, float2 g1, float2 z1,
                 float2 g2, float2 z2, float2 g3, float2 z3) -> float2 {
        float xx = g0.x * z0.x;      xx = fmaf(-g0.y, z0.y, xx);
        xx = fmaf(g1.x, z1.x, xx);   xx = fmaf(-g1.y, z1.y, xx);
        xx = fmaf(g2.x, z2.x, xx);   xx = fmaf(-g2.y, z2.y, xx);
        xx = fmaf(g3.x, z3.x, xx);   xx = fmaf(-g3.y, z3.y, xx);
        float yy = g0.x * z0.y;      yy = fmaf(g0.y, z0.x, yy);
        yy = fmaf(g1.x, z1.y, yy);   yy = fmaf(g1.y, z1.x, yy);
        yy = fmaf(g2.x, z2.y, yy);   yy = fmaf(g2.y, z2.x, yy);
        yy = fmaf(g3.x, z3.y, yy);   yy = fmaf(g3.y, z3.x, yy);
        return make_float2(xx, yy);
    };

    auto lstage_shfl = [&c4](float2 z[4], const float2* G, int h) {
        #pragma unroll
        for (int r = 0; r < 4; ++r) {
            const float2 u1 = make_float2(__shfl_xor(z[r].x, h),
                                          __shfl_xor(z[r].y, h));
            const float2 u2 = make_float2(__shfl_xor(z[r].x, 2 * h),
                                          __shfl_xor(z[r].y, 2 * h));
            const float2 u3 = make_float2(__shfl_xor(z[r].x, 3 * h),
                                          __shfl_xor(z[r].y, 3 * h));
            z[r] = c4(G[0], z[r], G[1], u1, G[2], u2, G[3], u3);
        }
    };
    auto lstage_dpp = [&c4](float2 z[4], const float2* G) {
        #pragma unroll
        for (int r = 0; r < 4; ++r) {
            const float2 u1 = make_float2(dppf<0xB1>(z[r].x), dppf<0xB1>(z[r].y));
            const float2 u2 = make_float2(dppf<0x4E>(z[r].x), dppf<0x4E>(z[r].y));
            const float2 u3 = make_float2(dppf<0x1B>(z[r].x), dppf<0x1B>(z[r].y));
            z[r] = c4(G[0], z[r], G[1], u1, G[2], u2, G[3], u3);
        }
    };
    // fused quad stage with per-register coefficient rows Cf[r]
    auto lstage_dpp_C = [&c4, &Cf](float2 z[4]) {
        #pragma unroll
        for (int r = 0; r < 4; ++r) {
            const float2 u1 = make_float2(dppf<0xB1>(z[r].x), dppf<0xB1>(z[r].y));
            const float2 u2 = make_float2(dppf<0x4E>(z[r].x), dppf<0x4E>(z[r].y));
            const float2 u3 = make_float2(dppf<0x1B>(z[r].x), dppf<0x1B>(z[r].y));
            z[r] = c4(Cf[r][0], z[r], Cf[r][1], u1, Cf[r][2], u2, Cf[r][3], u3);
        }
    };

    // forward FFT-1024 minus its final quad stage (shared by all paths)
    auto fwd_head = [&](float2 z[4]) {
        radix4f(z[0], z[1], z[2], z[3], TA[0], TA[1], TA[2]);
        bufT[sb + tt] = z[0]; bufT[sb + 256 + tt] = z[1];
        bufT[sb + 512 + tt] = z[2]; bufT[sb + 768 + tt] = z[3];
        __syncthreads();
        z[0] = bufT[sb + w * 256 + l];       z[1] = bufT[sb + w * 256 + 64 + l];
        z[2] = bufT[sb + w * 256 + 128 + l]; z[3] = bufT[sb + w * 256 + 192 + l];
        radix4f(z[0], z[1], z[2], z[3], TB[0], TB[1], TB[2]);
        lstage_shfl(z, GF[0], 16);
        lstage_shfl(z, GF[1], 4);
    };

    // inverse FFT-1024 minus its first quad stage
    auto inv_tail = [&](float2 z[4], float ur[4]) {
        lstage_shfl(z, GI[1], 4);
        lstage_shfl(z, GI[2], 16);
        const float2 g0 = z[0];
        const float2 g1 = make_float2(z[1].x * TB[0].x + z[1].y * TB[0].y,
                                      z[1].y * TB[0].x - z[1].x * TB[0].y);
        const float2 g2 = make_float2(z[2].x * TB[1].x + z[2].y * TB[1].y,
                                      z[2].y * TB[1].x - z[2].x * TB[1].y);
        const float2 g3 = make_float2(z[3].x * TB[2].x + z[3].y * TB[2].y,
                                      z[3].y * TB[2].x - z[3].x * TB[2].y);
        const float2 apc = make_float2(g0.x + g2.x, g0.y + g2.y);
        const float2 amc = make_float2(g0.x - g2.x, g0.y - g2.y);
        const float2 bpd = make_float2(g1.x + g3.x, g1.y + g3.y);
        const float2 bmd = make_float2(g1.x - g3.x, g1.y - g3.y);
        bufT2[sb + w * 256 + l]       = make_float2(apc.x + bpd.x, apc.y + bpd.y);
        bufT2[sb + w * 256 + 64 + l]  = make_float2(amc.x - bmd.y, amc.y + bmd.x);
        bufT2[sb + w * 256 + 128 + l] = make_float2(apc.x - bpd.x, apc.y - bpd.y);
        bufT2[sb + w * 256 + 192 + l] = make_float2(amc.x + bmd.y, amc.y - bmd.x);
        __syncthreads();
        const float2 h0 = bufT2[sb + tt];
        const float2 h1 = bufT2[sb + 256 + tt];
        const float2 h2 = bufT2[sb + 512 + tt];
        const float2 h3 = bufT2[sb + 768 + tt];
        const float g1x = h1.x * TA[0].x + h1.y * TA[0].y;
        const float g1y = h1.y * TA[0].x - h1.x * TA[0].y;
        const float g2x = h2.x * TA[1].x + h2.y * TA[1].y;
        const float g3x = h3.x * TA[2].x + h3.y * TA[2].y;
        const float g3y = h3.y * TA[2].x - h3.x * TA[2].y;
        ur[0] = h0.x + g1x + g2x + g3x;
        ur[1] = h0.x - g1y - g2x + g3y;
        ur[2] = h0.x - g1x + g2x - g3x;
        ur[3] = h0.x + g1y - g2x - g3y;
    };

    // ---- init: d_to_u (full fwd + pointwise + full inv) ----
    float2 z[4];
    float ur[4];
    #pragma unroll
    for (int j = 0; j < 4; ++j)
        z[j] = make_float2(x[b * NFFT + tt + 256 * j], 0.0f);
    fwd_head(z);
    lstage_dpp(z, GF[2]);
    #pragma unroll
    for (int r2 = 0; r2 < 4; ++r2) {
        const float zx = z[r2].x, zy = z[r2].y;
        z[r2] = make_float2(-zy * si[r2], zx * si[r2]);   // i*k*Z / N
    }
    lstage_dpp(z, GI[0]);
    inv_tail(z, ur);

    for (int ot = 0; ot < nT; ++ot) {
        for (int ss = 0; ss < nsub; ++ss) {
            #pragma unroll
            for (int j = 0; j < 4; ++j)
                z[j] = make_float2(ur[j], 0.5f * ur[j] * ur[j]);
            fwd_head(z);
            lstage_dpp_C(z);      // fused: fwd h=1 stage + S scale + inv h=1 stage
            inv_tail(z, ur);
        }
        // snapshot: u_to_d
        #pragma unroll
        for (int j = 0; j < 4; ++j)
            z[j] = make_float2(ur[j], 0.0f);
        fwd_head(z);
        lstage_dpp(z, GF[2]);
        #pragma unroll
        for (int r2 = 0; r2 < 4; ++r2) {
            const float zx = z[r2].x, zy = z[r2].y;
            z[r2] = make_float2(zy * csn[r2], -zx * csn[r2]);  // -i*Z/(N*k)
        }
        lstage_dpp(z, GI[0]);
        float dr[4];
        inv_tail(z, dr);
        #pragma unroll
        for (int j = 0; j < 4; ++j)
            out[(b * NFFT + tt + 256 * j) * nT + ot] = dr[j];
    }
}

extern "C" void kernel_launch(void* const* d_in, const int* in_sizes, int n_in,
                              void* d_out, int out_size, void* d_ws, size_t ws_size,
                              hipStream_t stream) {
    const float* x     = (const float*)d_in[0];
    const float* nu_p  = (const float*)d_in[1];
    const float* dto_p = (const float*)d_in[2];
    const float* cr_p  = (const float*)d_in[3];
    const int*   nt_p  = (const int*)d_in[4];
    const int*   ns_p  = (const int*)d_in[5];
    float* out = (float*)d_out;

    const int B = in_sizes[0] / NFFT;  // C == 1
    siva_kernel<<<B / 2, BLK, 0, stream>>>(x, nu_p, dto_p, cr_p, nt_p, ns_p, out);
}

// Round 6
// 772.749 us; speedup vs baseline: 2.0125x; 2.0125x over previous
//
#include <hip/hip_runtime.h>
#include <math.h>

#define NFFT 1024
#define BLK  512   // 8 waves, ONE batch per block -> 2 waves/SIMD, grid stays 128

// ---- DPP cross-lane (VALU pipe) ----
template <int CTRL>
__device__ __forceinline__ float dppf(float v) {
    return __int_as_float(__builtin_amdgcn_update_dpp(
        0, __float_as_int(v), CTRL, 0xF, 0xF, true));
}
// quad_perm: lane^1, lane^2, lane^3 (verified in Round 4)
__device__ __forceinline__ float qx1(float v) { return dppf<0xB1>(v); }
__device__ __forceinline__ float qx2(float v) { return dppf<0x4E>(v); }
__device__ __forceinline__ float qx3(float v) { return dppf<0x1B>(v); }
// row ops within 16-lane row: lane^4 = half_mirror then quad-reverse; lane^8 = row_ror:8
__device__ __forceinline__ float xr4(float v) { return dppf<0x1B>(dppf<0x141>(v)); }
__device__ __forceinline__ float xr8(float v) { return dppf<0x128>(v); }

__global__ __launch_bounds__(BLK)
void siva_kernel(const float* __restrict__ x,
                 const float* __restrict__ nu_p,
                 const float* __restrict__ dto_p,
                 const float* __restrict__ cr_p,
                 const int* __restrict__ nt_p,
                 const int* __restrict__ ns_p,
                 float* __restrict__ out) {
    __shared__ float2 bufG[NFFT];    // fwd radix-8 gather: seqA [0..511], seqB [512..1023]
    __shared__ float2 bufG2[NFFT];   // inv radix-8 gather

    const int tt = threadIdx.x;      // 0..511
    const int b  = blockIdx.x;
    const int l  = tt & 63;
    const int w  = tt >> 6;          // wave 0..7 = radix-8 slot s
    // radix-4 digit reversal of lane: l = 16a+4b2+c -> R = a + 4*b2 + 16*c
    const int R = (l >> 4) | (l & 12) | ((l & 3) << 4);

    const int nT   = nt_p[0];
    const int nsub = ns_p[0];

    const float nu  = (1.0f / (1.0f + expf(-nu_p[0])))  * (0.5f - 0.01f)  + 0.01f;
    const float dto = (1.0f / (1.0f + expf(-dto_p[0]))) * (0.1f - 0.001f) + 0.001f;
    const float cR  = (1.0f / (1.0f + expf(-cr_p[0])))  * (2.0f - 0.5f)   + 0.5f;
    const float dt   = dto / (float)nsub;
    const float dtcR = dt * cR;

    // radix-2 twiddle W_1024^{tt}
    float2 T10;
    { const float a = (float)tt * (1.0f / 512.0f);
      T10 = make_float2(cospif(a), -sinpif(a)); }

    // radix-8 gather coefficients.
    // fwd (own slot s=w), input j=w': E8f[j] = W8^{j*w} * W512^{l*w}
    // inv (own w), input j=s:        D8[j] = conj(W8^{w*j} * W512^{l*j})
    float2 E8f[8], D8[8];
    #pragma unroll
    for (int j = 0; j < 8; ++j) {
        const float af = (float)(j * w) * 0.25f + (float)(l * w) * (1.0f / 256.0f);
        E8f[j] = make_float2(cospif(af), -sinpif(af));
        const float ai = (float)(w * j) * 0.25f + (float)(l * j) * (1.0f / 256.0f);
        D8[j] = make_float2(cospif(ai), sinpif(ai));
    }

    // Lane-FFT radix-4 per-stage per-lane weights (verified Round 4 machinery).
    float2 GF[3][4], GI[3][4];
    {
        const int hs[3] = {16, 4, 1};
        #pragma unroll
        for (int s = 0; s < 3; ++s) {
            const int h = hs[s];
            const int a = (l / h) & 3;
            const int m = l % h;
            const float invM = 1.0f / (float)(4 * h);
            #pragma unroll
            for (int d = 0; d < 4; ++d) {
                const int e4 = ((d ^ a) * a) & 3;
                const float angF = 0.5f * (float)e4
                                 + 2.0f * (float)(a * m) * invM;   // pi units
                GF[s][d] = make_float2(cospif(angF), -sinpif(angF));
                const float angI = 0.5f * (float)e4
                                 + 2.0f * (float)((d ^ a) * m) * invM;
                GI[2 - s][d] = make_float2(cospif(angI), sinpif(angI));
            }
        }
    }

    // Spectral constants. k = 16*R + 2*w + p.
    float Sc[2], csn[2], si[2];
    #pragma unroll
    for (int p = 0; p < 2; ++p) {
        const int k = 16 * R + 2 * w + p;
        const float kk = (k <= 512) ? (float)k : (float)(k - 1024);
        const float ka = fabsf(kk);
        const float q  = 1.0f - dtcR * (ka - nu * ka * ka);
        const float a  = (1.0f / q) * (1.0f / 1024.0f);
        const float kkS = (k == 0 || k == 512) ? 0.0f : kk;
        Sc[p]  = a * (1.0f - dt * kkS);
        csn[p] = (k == 0) ? 0.0f : (1.0f / (1024.0f * kk));
        si[p]  = kk * (1.0f / 1024.0f);
    }

    // Fused quad operator (fwd h=1 stage + S scale + inv h=1 stage).
    float2 Cf[2][4];
    #pragma unroll
    for (int p = 0; p < 2; ++p) {
        #pragma unroll
        for (int e = 0; e < 4; ++e) {
            float cx = 0.0f, cy = 0.0f;
            #pragma unroll
            for (int d = 0; d < 4; ++d) {
                const float sd = __shfl_xor(Sc[p], d);
                const float gx = __shfl_xor(GF[2][d ^ e].x, d);
                const float gy = __shfl_xor(GF[2][d ^ e].y, d);
                const float2 gi = GI[0][d];
                cx = fmaf(sd, gi.x * gx - gi.y * gy, cx);
                cy = fmaf(sd, gi.x * gy + gi.y * gx, cy);
            }
            Cf[p][e] = make_float2(cx, cy);
        }
    }

    // y = g0*z0 + g1*z1 + g2*z2 + g3*z3 (complex)
    auto c4 = [](float2 g0, float2 z0, float2 g1, float2 z1,
                 float2 g2, float2 z2, float2 g3, float2 z3) -> float2 {
        float xx = g0.x * z0.x;      xx = fmaf(-g0.y, z0.y, xx);
        xx = fmaf(g1.x, z1.x, xx);   xx = fmaf(-g1.y, z1.y, xx);
        xx = fmaf(g2.x, z2.x, xx);   xx = fmaf(-g2.y, z2.y, xx);
        xx = fmaf(g3.x, z3.x, xx);   xx = fmaf(-g3.y, z3.y, xx);
        float yy = g0.x * z0.y;      yy = fmaf(g0.y, z0.x, yy);
        yy = fmaf(g1.x, z1.y, yy);   yy = fmaf(g1.y, z1.x, yy);
        yy = fmaf(g2.x, z2.y, yy);   yy = fmaf(g2.y, z2.x, yy);
        yy = fmaf(g3.x, z3.y, yy);   yy = fmaf(g3.y, z3.x, yy);
        return make_float2(xx, yy);
    };

    // Sum_{j=0..7} c[j]*v[j] (complex)
    auto csum8 = [](const float2* c, const float2* v) -> float2 {
        float xx = c[0].x * v[0].x;  xx = fmaf(-c[0].y, v[0].y, xx);
        float yy = c[0].x * v[0].y;  yy = fmaf(c[0].y, v[0].x, yy);
        #pragma unroll
        for (int j = 1; j < 8; ++j) {
            xx = fmaf(c[j].x, v[j].x, xx);  xx = fmaf(-c[j].y, v[j].y, xx);
            yy = fmaf(c[j].x, v[j].y, yy);  yy = fmaf(c[j].y, v[j].x, yy);
        }
        return make_float2(xx, yy);
    };

    auto stage16 = [&c4](float2 z[2], const float2* G) {
        #pragma unroll
        for (int r = 0; r < 2; ++r) {
            const float2 u1 = make_float2(__shfl_xor(z[r].x, 16), __shfl_xor(z[r].y, 16));
            const float2 u2 = make_float2(__shfl_xor(z[r].x, 32), __shfl_xor(z[r].y, 32));
            const float2 u3 = make_float2(__shfl_xor(z[r].x, 48), __shfl_xor(z[r].y, 48));
            z[r] = c4(G[0], z[r], G[1], u1, G[2], u2, G[3], u3);
        }
    };
    auto stage4dpp = [&c4](float2 z[2], const float2* G) {
        #pragma unroll
        for (int r = 0; r < 2; ++r) {
            const float2 u1 = make_float2(xr4(z[r].x), xr4(z[r].y));   // l^4
            const float2 u2 = make_float2(xr8(z[r].x), xr8(z[r].y));   // l^8
            const float2 u3 = make_float2(xr8(u1.x),   xr8(u1.y));     // l^12
            z[r] = c4(G[0], z[r], G[1], u1, G[2], u2, G[3], u3);
        }
    };
    auto stageQuad = [&c4](float2 z[2], const float2* G) {
        #pragma unroll
        for (int r = 0; r < 2; ++r) {
            const float2 u1 = make_float2(qx1(z[r].x), qx1(z[r].y));
            const float2 u2 = make_float2(qx2(z[r].x), qx2(z[r].y));
            const float2 u3 = make_float2(qx3(z[r].x), qx3(z[r].y));
            z[r] = c4(G[0], z[r], G[1], u1, G[2], u2, G[3], u3);
        }
    };
    auto stageQuadC = [&c4, &Cf](float2 z[2]) {
        #pragma unroll
        for (int p = 0; p < 2; ++p) {
            const float2 u1 = make_float2(qx1(z[p].x), qx1(z[p].y));
            const float2 u2 = make_float2(qx2(z[p].x), qx2(z[p].y));
            const float2 u3 = make_float2(qx3(z[p].x), qx3(z[p].y));
            z[p] = c4(Cf[p][0], z[p], Cf[p][1], u1, Cf[p][2], u2, Cf[p][3], u3);
        }
    };

    // fwd head: z[0]=z(tt), z[1]=z(tt+512) -> radix-2 -> LDS radix-8 gather -> lane h=16,h=4
    auto fwd_head = [&](float2 z[2]) {
        const float2 A  = make_float2(z[0].x + z[1].x, z[0].y + z[1].y);
        const float2 Dm = make_float2(z[0].x - z[1].x, z[0].y - z[1].y);
        const float2 Bc = make_float2(Dm.x * T10.x - Dm.y * T10.y,
                                      Dm.x * T10.y + Dm.y * T10.x);
        bufG[tt] = A;  bufG[512 + tt] = Bc;
        __syncthreads();
        float2 ra[8], rb[8];
        #pragma unroll
        for (int j = 0; j < 8; ++j) {
            ra[j] = bufG[64 * j + l];
            rb[j] = bufG[512 + 64 * j + l];
        }
        z[0] = csum8(E8f, ra);
        z[1] = csum8(E8f, rb);
        stage16(z, GF[0]);
        stage4dpp(z, GF[1]);
    };

    // inv tail: lane h=4,h=16 -> LDS radix-8 inverse gather -> radix-2 inverse (REAL parts)
    auto inv_tail = [&](float2 z[2], float& u0, float& u1) {
        stage4dpp(z, GI[1]);
        stage16(z, GI[2]);
        bufG2[tt] = z[0];  bufG2[512 + tt] = z[1];
        __syncthreads();
        float2 ya[8], yb[8];
        #pragma unroll
        for (int j = 0; j < 8; ++j) {
            ya[j] = bufG2[64 * j + l];
            yb[j] = bufG2[512 + 64 * j + l];
        }
        const float2 vA = csum8(D8, ya);
        const float2 vB = csum8(D8, yb);
        const float re = vB.x * T10.x + vB.y * T10.y;   // Re(vB * conj(T10))
        u0 = vA.x + re;
        u1 = vA.x - re;
    };

    // ---- init: d_to_u ----
    float2 z[2];
    float u0, u1;
    z[0] = make_float2(x[b * NFFT + tt], 0.0f);
    z[1] = make_float2(x[b * NFFT + tt + 512], 0.0f);
    fwd_head(z);
    stageQuad(z, GF[2]);
    #pragma unroll
    for (int p = 0; p < 2; ++p) {
        const float zx = z[p].x, zy = z[p].y;
        z[p] = make_float2(-zy * si[p], zx * si[p]);   // i*k*Z / N
    }
    stageQuad(z, GI[0]);
    inv_tail(z, u0, u1);

    for (int ot = 0; ot < nT; ++ot) {
        for (int ss = 0; ss < nsub; ++ss) {
            z[0] = make_float2(u0, 0.5f * u0 * u0);
            z[1] = make_float2(u1, 0.5f * u1 * u1);
            fwd_head(z);
            stageQuadC(z);     // fused: fwd h=1 + S scale + inv h=1
            inv_tail(z, u0, u1);
        }
        // snapshot: u_to_d
        z[0] = make_float2(u0, 0.0f);
        z[1] = make_float2(u1, 0.0f);
        fwd_head(z);
        stageQuad(z, GF[2]);
        #pragma unroll
        for (int p = 0; p < 2; ++p) {
            const float zx = z[p].x, zy = z[p].y;
            z[p] = make_float2(zy * csn[p], -zx * csn[p]);  // -i*Z/(N*k)
        }
        stageQuad(z, GI[0]);
        float d0, d1;
        inv_tail(z, d0, d1);
        out[(b * NFFT + tt) * nT + ot]       = d0;
        out[(b * NFFT + tt + 512) * nT + ot] = d1;
    }
}

extern "C" void kernel_launch(void* const* d_in, const int* in_sizes, int n_in,
                              void* d_out, int out_size, void* d_ws, size_t ws_size,
                              hipStream_t stream) {
    const float* x     = (const float*)d_in[0];
    const float* nu_p  = (const float*)d_in[1];
    const float* dto_p = (const float*)d_in[2];
    const float* cr_p  = (const float*)d_in[3];
    const int*   nt_p  = (const int*)d_in[4];
    const int*   ns_p  = (const int*)d_in[5];
    float* out = (float*)d_out;

    const int B = in_sizes[0] / NFFT;  // C == 1
    siva_kernel<<<B, BLK, 0, stream>>>(x, nu_p, dto_p, cr_p, nt_p, ns_p, out);
}

// Round 7
// 749.264 us; speedup vs baseline: 2.0756x; 1.0313x over previous
//
#include <hip/hip_runtime.h>
#include <math.h>

#define NFFT 1024
#define BLK  512   // 8 waves, ONE batch per block; grid = 128

// ---- DPP cross-lane (VALU pipe), all validated on HW in Round 6 ----
template <int CTRL>
__device__ __forceinline__ float dppf(float v) {
    return __int_as_float(__builtin_amdgcn_update_dpp(
        0, __float_as_int(v), CTRL, 0xF, 0xF, true));
}
__device__ __forceinline__ float qx1(float v) { return dppf<0xB1>(v); }   // l^1
__device__ __forceinline__ float qx2(float v) { return dppf<0x4E>(v); }   // l^2
__device__ __forceinline__ float xr4(float v) { return dppf<0x1B>(dppf<0x141>(v)); } // l^4
__device__ __forceinline__ float xr8(float v) { return dppf<0x128>(v); }  // l^8

__global__ __launch_bounds__(BLK)
void siva_kernel(const float* __restrict__ x,
                 const float* __restrict__ nu_p,
                 const float* __restrict__ dto_p,
                 const float* __restrict__ cr_p,
                 const int* __restrict__ nt_p,
                 const int* __restrict__ ns_p,
                 float* __restrict__ out) {
    __shared__ float4 bufF[BLK];   // fwd radix-8 gather, A/B interleaved
    __shared__ float4 bufI[BLK];   // inv radix-8 gather

    const int tt = threadIdx.x;    // 0..511
    const int b  = blockIdx.x;
    const int l  = tt & 63;
    const int w  = tt >> 6;        // wave 0..7 = radix-8 slot
    const int R  = (int)(__brev((unsigned)l) >> 26);   // rev6(l)

    const int nT   = nt_p[0];
    const int nsub = ns_p[0];

    const float nu  = (1.0f / (1.0f + expf(-nu_p[0])))  * (0.5f - 0.01f)  + 0.01f;
    const float dto = (1.0f / (1.0f + expf(-dto_p[0]))) * (0.1f - 0.001f) + 0.001f;
    const float cR  = (1.0f / (1.0f + expf(-cr_p[0])))  * (2.0f - 0.5f)   + 0.5f;
    const float dt   = dto / (float)nsub;
    const float dtcR = dt * cR;

    // radix-2 reg-digit twiddle W1024^{tt}
    float2 T10;
    { const float a = (float)tt * (1.0f / 512.0f);
      T10 = make_float2(cospif(a), -sinpif(a)); }

    // radix-8 gather coefficients (Round-6 verified).
    float2 E8f[8], D8[8];
    #pragma unroll
    for (int j = 0; j < 8; ++j) {
        const float af = (float)(j * w) * 0.25f + (float)(l * w) * (1.0f / 256.0f);
        E8f[j] = make_float2(cospif(af), -sinpif(af));
        const float ai = (float)(w * j) * 0.25f + (float)(l * j) * (1.0f / 256.0f);
        D8[j] = make_float2(cospif(ai), sinpif(ai));
    }

    // Lane-64 radix-2 tables (Round-2 verified machinery).
    // fwd DIF: s=0..5, h=32>>s. inv DIT: s=0..5, h=1<<s.
    float2 wf[6]; float sg[6]; float2 wi[6];
    #pragma unroll
    for (int s = 0; s < 6; ++s) {
        const int h = 32 >> s;
        const int lm = l & (h - 1);
        const bool hi = (l & h) != 0;
        const float a = (float)(lm * (32 / h)) * (1.0f / 32.0f);   // pi units
        wf[s] = hi ? make_float2(cospif(a), -sinpif(a)) : make_float2(1.0f, 0.0f);
        sg[s] = hi ? -1.0f : 1.0f;
        const int h2 = 1 << s;
        const int lm2 = l & (h2 - 1);
        const float a2 = (float)lm2 / (float)h2;
        float2 wb = make_float2(cospif(a2), sinpif(a2));
        if ((l & h2) != 0) { wb.x = -wb.x; wb.y = -wb.y; }
        wi[s] = wb;
    }
    const bool m2 = (l & 2) != 0, m4 = (l & 4) != 0, m8 = (l & 8) != 0,
               m16 = (l & 16) != 0, m32 = (l & 32) != 0;

    // Spectral constants. k = 16*rev6(l) + 2*w + p.
    float Sc[2], csn[2], si[2];
    #pragma unroll
    for (int p = 0; p < 2; ++p) {
        const int k = 16 * R + 2 * w + p;
        const float kk = (k <= 512) ? (float)k : (float)(k - 1024);
        const float ka = fabsf(kk);
        const float q  = 1.0f - dtcR * (ka - nu * ka * ka);
        const float a  = (1.0f / q) * (1.0f / 1024.0f);
        const float kkS = (k == 0 || k == 512) ? 0.0f : kk;
        Sc[p]  = a * (1.0f - dt * kkS);
        csn[p] = (k == 0) ? 0.0f : (1.0f / (1024.0f * kk));
        si[p]  = kk * (1.0f / 1024.0f);
    }
    // Fused pair operator (fwd h=1 + S + inv h=1): out = A2*z + B2*z^(l^1), real coeffs.
    float A2[2], B2[2];
    { const float sg1 = (l & 1) ? -1.0f : 1.0f;
      #pragma unroll
      for (int p = 0; p < 2; ++p) {
          const float so = __shfl_xor(Sc[p], 1);
          A2[p] = Sc[p] + so;
          B2[p] = sg1 * (Sc[p] - so);
      } }

    // fwd DIF step: z = wf[s] * (partner + sg[s]*z)
    auto fwd_s = [&](float2& zz, float bx, float by, int s) {
        const float tx = fmaf(sg[s], zz.x, bx);
        const float ty = fmaf(sg[s], zz.y, by);
        zz.x = tx * wf[s].x - ty * wf[s].y;
        zz.y = tx * wf[s].y + ty * wf[s].x;
    };
    // inv DIT step: z = q + wi[s]*p  (p = high-half value, q = low-half value)
    auto inv_s = [&](float2& zz, float bx, float by, int s, bool hi) {
        const float px = hi ? zz.x : bx, py = hi ? zz.y : by;
        const float qx = hi ? bx : zz.x, qy = hi ? by : zz.y;
        zz.x = qx + px * wi[s].x - py * wi[s].y;
        zz.y = qy + px * wi[s].y + py * wi[s].x;
    };

    // fwd lane chain, stages h=32,16 (shfl) and 8,4,2 (DPP). h=1 handled by caller.
    auto lane_fwd5 = [&](float2 z[2]) {
        #pragma unroll
        for (int r = 0; r < 2; ++r)
            fwd_s(z[r], __shfl_xor(z[r].x, 32), __shfl_xor(z[r].y, 32), 0);
        #pragma unroll
        for (int r = 0; r < 2; ++r)
            fwd_s(z[r], __shfl_xor(z[r].x, 16), __shfl_xor(z[r].y, 16), 1);
        #pragma unroll
        for (int r = 0; r < 2; ++r) fwd_s(z[r], xr8(z[r].x), xr8(z[r].y), 2);
        #pragma unroll
        for (int r = 0; r < 2; ++r) fwd_s(z[r], xr4(z[r].x), xr4(z[r].y), 3);
        #pragma unroll
        for (int r = 0; r < 2; ++r) fwd_s(z[r], qx2(z[r].x), qx2(z[r].y), 4);
    };
    // inv lane chain, stages h=2,4,8 (DPP) and 16,32 (shfl). h=1 handled by caller.
    auto lane_inv5 = [&](float2 z[2]) {
        #pragma unroll
        for (int r = 0; r < 2; ++r) inv_s(z[r], qx2(z[r].x), qx2(z[r].y), 1, m2);
        #pragma unroll
        for (int r = 0; r < 2; ++r) inv_s(z[r], xr4(z[r].x), xr4(z[r].y), 2, m4);
        #pragma unroll
        for (int r = 0; r < 2; ++r) inv_s(z[r], xr8(z[r].x), xr8(z[r].y), 3, m8);
        #pragma unroll
        for (int r = 0; r < 2; ++r)
            inv_s(z[r], __shfl_xor(z[r].x, 16), __shfl_xor(z[r].y, 16), 4, m16);
        #pragma unroll
        for (int r = 0; r < 2; ++r)
            inv_s(z[r], __shfl_xor(z[r].x, 32), __shfl_xor(z[r].y, 32), 5, m32);
    };

    // fwd head: z[0]=x(tt), z[1]=x(tt+512) -> radix-2 -> LDS radix-8 gather -> lane 5 stages
    auto fwd_head = [&](float2 z[2]) {
        const float2 A  = make_float2(z[0].x + z[1].x, z[0].y + z[1].y);
        const float2 Dm = make_float2(z[0].x - z[1].x, z[0].y - z[1].y);
        const float2 Bc = make_float2(Dm.x * T10.x - Dm.y * T10.y,
                                      Dm.x * T10.y + Dm.y * T10.x);
        bufF[tt] = make_float4(A.x, A.y, Bc.x, Bc.y);
        __syncthreads();
        float2 za = make_float2(0.0f, 0.0f), zb = make_float2(0.0f, 0.0f);
        #pragma unroll
        for (int j = 0; j < 8; ++j) {
            const float4 v = bufF[64 * j + l];
            za.x = fmaf(E8f[j].x, v.x, za.x);  za.x = fmaf(-E8f[j].y, v.y, za.x);
            za.y = fmaf(E8f[j].x, v.y, za.y);  za.y = fmaf(E8f[j].y, v.x, za.y);
            zb.x = fmaf(E8f[j].x, v.z, zb.x);  zb.x = fmaf(-E8f[j].y, v.w, zb.x);
            zb.y = fmaf(E8f[j].x, v.w, zb.y);  zb.y = fmaf(E8f[j].y, v.z, zb.y);
        }
        z[0] = za; z[1] = zb;
        lane_fwd5(z);
    };

    // inv tail: lane 5 stages -> LDS radix-8 inverse gather -> radix-2 inverse, REAL only
    auto inv_tail = [&](float2 z[2], float& u0o, float& u1o) {
        lane_inv5(z);
        bufI[tt] = make_float4(z[0].x, z[0].y, z[1].x, z[1].y);
        __syncthreads();
        float vAx = 0.0f, vBx = 0.0f, vBy = 0.0f;
        #pragma unroll
        for (int j = 0; j < 8; ++j) {
            const float4 v = bufI[64 * j + l];
            vAx = fmaf(D8[j].x, v.x, vAx);  vAx = fmaf(-D8[j].y, v.y, vAx);
            vBx = fmaf(D8[j].x, v.z, vBx);  vBx = fmaf(-D8[j].y, v.w, vBx);
            vBy = fmaf(D8[j].x, v.w, vBy);  vBy = fmaf(D8[j].y, v.z, vBy);
        }
        const float re = vBx * T10.x + vBy * T10.y;   // Re(vB * conj(T10))
        u0o = vAx + re;
        u1o = vAx - re;
    };

    // ---- init: d_to_u (full unfused fwd + pointwise + full unfused inv) ----
    float2 z[2];
    float u0, u1;
    z[0] = make_float2(x[b * NFFT + tt], 0.0f);
    z[1] = make_float2(x[b * NFFT + tt + 512], 0.0f);
    fwd_head(z);
    #pragma unroll
    for (int r = 0; r < 2; ++r) fwd_s(z[r], qx1(z[r].x), qx1(z[r].y), 5);  // h=1
    #pragma unroll
    for (int p = 0; p < 2; ++p) {
        const float zx = z[p].x, zy = z[p].y;
        z[p] = make_float2(-zy * si[p], zx * si[p]);   // i*k*Z / N
    }
    { const bool m1 = (l & 1) != 0;
      #pragma unroll
      for (int r = 0; r < 2; ++r) inv_s(z[r], qx1(z[r].x), qx1(z[r].y), 0, m1); }
    inv_tail(z, u0, u1);

    for (int ot = 0; ot < nT; ++ot) {
        for (int ss = 0; ss < nsub; ++ss) {
            z[0] = make_float2(u0, 0.5f * u0 * u0);
            z[1] = make_float2(u1, 0.5f * u1 * u1);
            fwd_head(z);
            // fused: fwd h=1 + S scale + inv h=1 (real coefficients)
            #pragma unroll
            for (int p = 0; p < 2; ++p) {
                const float px = qx1(z[p].x), py = qx1(z[p].y);
                z[p].x = fmaf(A2[p], z[p].x, B2[p] * px);
                z[p].y = fmaf(A2[p], z[p].y, B2[p] * py);
            }
            inv_tail(z, u0, u1);
        }
        // snapshot: u_to_d (unfused)
        z[0] = make_float2(u0, 0.0f);
        z[1] = make_float2(u1, 0.0f);
        fwd_head(z);
        #pragma unroll
        for (int r = 0; r < 2; ++r) fwd_s(z[r], qx1(z[r].x), qx1(z[r].y), 5);
        #pragma unroll
        for (int p = 0; p < 2; ++p) {
            const float zx = z[p].x, zy = z[p].y;
            z[p] = make_float2(zy * csn[p], -zx * csn[p]);  // -i*Z/(N*k)
        }
        { const bool m1 = (l & 1) != 0;
          #pragma unroll
          for (int r = 0; r < 2; ++r) inv_s(z[r], qx1(z[r].x), qx1(z[r].y), 0, m1); }
        float d0, d1;
        inv_tail(z, d0, d1);
        out[(b * NFFT + tt) * nT + ot]       = d0;
        out[(b * NFFT + tt + 512) * nT + ot] = d1;
    }
}

extern "C" void kernel_launch(void* const* d_in, const int* in_sizes, int n_in,
                              void* d_out, int out_size, void* d_ws, size_t ws_size,
                              hipStream_t stream) {
    const float* x     = (const float*)d_in[0];
    const float* nu_p  = (const float*)d_in[1];
    const float* dto_p = (const float*)d_in[2];
    const float* cr_p  = (const float*)d_in[3];
    const int*   nt_p  = (const int*)d_in[4];
    const int*   ns_p  = (const int*)d_in[5];
    float* out = (float*)d_out;

    const int B = in_sizes[0] / NFFT;  // C == 1
    siva_kernel<<<B, BLK, 0, stream>>>(x, nu_p, dto_p, cr_p, nt_p, ns_p, out);
}

// Round 10
// 701.928 us; speedup vs baseline: 2.2155x; 1.0674x over previous
//
#include <hip/hip_runtime.h>
#include <math.h>

#define NFFT 1024
#define BLK  512   // 8 waves, ONE batch per block; grid = 128

// ---- DPP cross-lane (VALU pipe), HW-validated in Round 6 ----
// NOTE: packed ext_vector_type(2) float math is BANNED (R8/R9: identical wrong
// output from two different cross-lane impls => bug is in the packed core).
// permlane swap BUILTINS are exonerated by the same evidence (R8 h16/32 path
// == R9 verified shfl path). Raw permlane asm (R3) remains banned.
template <int CTRL>
__device__ __forceinline__ float dppf(float v) {
    return __int_as_float(__builtin_amdgcn_update_dpp(
        0, __float_as_int(v), CTRL, 0xF, 0xF, true));
}
__device__ __forceinline__ float qx1(float v) { return dppf<0xB1>(v); }   // l^1
__device__ __forceinline__ float qx2(float v) { return dppf<0x4E>(v); }   // l^2
__device__ __forceinline__ float xr4(float v) { return dppf<0x1B>(dppf<0x141>(v)); } // l^4
__device__ __forceinline__ float xr8(float v) { return dppf<0x128>(v); }  // l^8

// permlane swaps: lo = value of the pair-member with lane bit {4,5}=0,
// broadcast to both lanes; hi = the bit=1 member likewise. VALU pipe.
__device__ __forceinline__ void pswap16(float v, float& lo, float& hi) {
    auto r = __builtin_amdgcn_permlane16_swap(__float_as_int(v), __float_as_int(v),
                                              false, false);
    lo = __int_as_float(r[0]);
    hi = __int_as_float(r[1]);
}
__device__ __forceinline__ void pswap32(float v, float& lo, float& hi) {
    auto r = __builtin_amdgcn_permlane32_swap(__float_as_int(v), __float_as_int(v),
                                              false, false);
    lo = __int_as_float(r[0]);
    hi = __int_as_float(r[1]);
}

__global__ __launch_bounds__(BLK, 2)
void siva_kernel(const float* __restrict__ x,
                 const float* __restrict__ nu_p,
                 const float* __restrict__ dto_p,
                 const float* __restrict__ cr_p,
                 const int* __restrict__ nt_p,
                 const int* __restrict__ ns_p,
                 float* __restrict__ out) {
    __shared__ float4 bufF[BLK];   // fwd radix-8 gather, A/B interleaved
    __shared__ float4 bufI[BLK];   // inv radix-8 gather

    const int tt = threadIdx.x;    // 0..511
    const int b  = blockIdx.x;
    const int l  = tt & 63;
    const int w  = tt >> 6;        // wave 0..7 = radix-8 slot
    const int R  = (int)(__brev((unsigned)l) >> 26);   // rev6(l)

    const int nT   = nt_p[0];
    const int nsub = ns_p[0];

    const float nu  = (1.0f / (1.0f + expf(-nu_p[0])))  * (0.5f - 0.01f)  + 0.01f;
    const float dto = (1.0f / (1.0f + expf(-dto_p[0]))) * (0.1f - 0.001f) + 0.001f;
    const float cR  = (1.0f / (1.0f + expf(-cr_p[0])))  * (2.0f - 0.5f)   + 0.5f;
    const float dt   = dto / (float)nsub;
    const float dtcR = dt * cR;

    // radix-2 reg-digit twiddle W1024^{tt}
    float2 T10;
    { const float a = (float)tt * (1.0f / 512.0f);
      T10 = make_float2(cospif(a), -sinpif(a)); }

    // radix-8 gather coefficients (Round-6 verified).
    float2 E8f[8], D8[8];
    #pragma unroll
    for (int j = 0; j < 8; ++j) {
        const float af = (float)(j * w) * 0.25f + (float)(l * w) * (1.0f / 256.0f);
        E8f[j] = make_float2(cospif(af), -sinpif(af));
        const float ai = (float)(w * j) * 0.25f + (float)(l * j) * (1.0f / 256.0f);
        D8[j] = make_float2(cospif(ai), sinpif(ai));
    }

    // Lane-64 radix-2 tables (Round-2 verified machinery).
    // fwd DIF: s=0..5, h=32>>s. inv DIT: s=0..5, h=1<<s.
    float2 wf[6]; float sg[6]; float2 wi[6];
    #pragma unroll
    for (int s = 0; s < 6; ++s) {
        const int h = 32 >> s;
        const int lm = l & (h - 1);
        const bool hif = (l & h) != 0;
        const float a = (float)(lm * (32 / h)) * (1.0f / 32.0f);   // pi units
        wf[s] = hif ? make_float2(cospif(a), -sinpif(a)) : make_float2(1.0f, 0.0f);
        sg[s] = hif ? -1.0f : 1.0f;
        const int h2 = 1 << s;
        const int lm2 = l & (h2 - 1);
        const float a2 = (float)lm2 / (float)h2;
        float2 wb = make_float2(cospif(a2), sinpif(a2));
        if ((l & h2) != 0) { wb.x = -wb.x; wb.y = -wb.y; }
        wi[s] = wb;
    }
    const bool m2 = (l & 2) != 0, m4 = (l & 4) != 0, m8 = (l & 8) != 0;

    // Spectral constants. k = 16*rev6(l) + 2*w + p.
    float Sc[2], csn[2], si[2];
    #pragma unroll
    for (int p = 0; p < 2; ++p) {
        const int k = 16 * R + 2 * w + p;
        const float kk = (k <= 512) ? (float)k : (float)(k - 1024);
        const float ka = fabsf(kk);
        const float q  = 1.0f - dtcR * (ka - nu * ka * ka);
        const float a  = (1.0f / q) * (1.0f / 1024.0f);
        const float kkS = (k == 0 || k == 512) ? 0.0f : kk;
        Sc[p]  = a * (1.0f - dt * kkS);
        csn[p] = (k == 0) ? 0.0f : (1.0f / (1024.0f * kk));
        si[p]  = kk * (1.0f / 1024.0f);
    }
    // Fused pair operator (fwd h=1 + S + inv h=1): out = A2*z + B2*z^(l^1), real.
    float A2[2], B2[2];
    { const float sg1 = (l & 1) ? -1.0f : 1.0f;
      #pragma unroll
      for (int p = 0; p < 2; ++p) {
          const float so = __shfl_xor(Sc[p], 1);
          A2[p] = Sc[p] + so;
          B2[p] = sg1 * (Sc[p] - so);
      } }

    // fwd DIF step: z = wf[s] * (partner + sg[s]*z)
    auto fwd_s = [&](float2& zz, float bx, float by, int s) {
        const float tx = fmaf(sg[s], zz.x, bx);
        const float ty = fmaf(sg[s], zz.y, by);
        zz.x = tx * wf[s].x - ty * wf[s].y;
        zz.y = tx * wf[s].y + ty * wf[s].x;
    };
    // inv DIT step: z = q + wi[s]*p  (p = high-half value, q = low-half value)
    auto inv_s = [&](float2& zz, float bx, float by, int s, bool hi) {
        const float px = hi ? zz.x : bx, py = hi ? zz.y : by;
        const float qx = hi ? bx : zz.x, qy = hi ? by : zz.y;
        zz.x = qx + px * wi[s].x - py * wi[s].y;
        zz.y = qy + px * wi[s].y + py * wi[s].x;
    };

    // fwd lane chain h=32,16 (permlane swap) + 8,4,2 (DPP). h=1 handled by caller.
    auto lane_fwd5 = [&](float2 z[2]) {
        #pragma unroll
        for (int r = 0; r < 2; ++r) {
            float lox, hix, loy, hiy;
            pswap32(z[r].x, lox, hix); pswap32(z[r].y, loy, hiy);
            const float tx = fmaf(sg[0], hix, lox);   // lo + sg*hi
            const float ty = fmaf(sg[0], hiy, loy);
            z[r].x = tx * wf[0].x - ty * wf[0].y;
            z[r].y = tx * wf[0].y + ty * wf[0].x;
        }
        #pragma unroll
        for (int r = 0; r < 2; ++r) {
            float lox, hix, loy, hiy;
            pswap16(z[r].x, lox, hix); pswap16(z[r].y, loy, hiy);
            const float tx = fmaf(sg[1], hix, lox);
            const float ty = fmaf(sg[1], hiy, loy);
            z[r].x = tx * wf[1].x - ty * wf[1].y;
            z[r].y = tx * wf[1].y + ty * wf[1].x;
        }
        #pragma unroll
        for (int r = 0; r < 2; ++r) fwd_s(z[r], xr8(z[r].x), xr8(z[r].y), 2);
        #pragma unroll
        for (int r = 0; r < 2; ++r) fwd_s(z[r], xr4(z[r].x), xr4(z[r].y), 3);
        #pragma unroll
        for (int r = 0; r < 2; ++r) fwd_s(z[r], qx2(z[r].x), qx2(z[r].y), 4);
    };
    // inv lane chain h=2,4,8 (DPP, select form) + 16,32 (permlane: z = lo + wi*hi).
    auto lane_inv5 = [&](float2 z[2]) {
        #pragma unroll
        for (int r = 0; r < 2; ++r) inv_s(z[r], qx2(z[r].x), qx2(z[r].y), 1, m2);
        #pragma unroll
        for (int r = 0; r < 2; ++r) inv_s(z[r], xr4(z[r].x), xr4(z[r].y), 2, m4);
        #pragma unroll
        for (int r = 0; r < 2; ++r) inv_s(z[r], xr8(z[r].x), xr8(z[r].y), 3, m8);
        #pragma unroll
        for (int r = 0; r < 2; ++r) {
            float lox, hix, loy, hiy;
            pswap16(z[r].x, lox, hix); pswap16(z[r].y, loy, hiy);
            z[r].x = fmaf(wi[4].x, hix, fmaf(-wi[4].y, hiy, lox));
            z[r].y = fmaf(wi[4].x, hiy, fmaf( wi[4].y, hix, loy));
        }
        #pragma unroll
        for (int r = 0; r < 2; ++r) {
            float lox, hix, loy, hiy;
            pswap32(z[r].x, lox, hix); pswap32(z[r].y, loy, hiy);
            z[r].x = fmaf(wi[5].x, hix, fmaf(-wi[5].y, hiy, lox));
            z[r].y = fmaf(wi[5].x, hiy, fmaf( wi[5].y, hix, loy));
        }
    };

    // fwd head: z[0]=x(tt), z[1]=x(tt+512) -> radix-2 -> LDS radix-8 gather -> lane 5 stages
    auto fwd_head = [&](float2 z[2]) {
        const float2 A  = make_float2(z[0].x + z[1].x, z[0].y + z[1].y);
        const float2 Dm = make_float2(z[0].x - z[1].x, z[0].y - z[1].y);
        const float2 Bc = make_float2(Dm.x * T10.x - Dm.y * T10.y,
                                      Dm.x * T10.y + Dm.y * T10.x);
        bufF[tt] = make_float4(A.x, A.y, Bc.x, Bc.y);
        __syncthreads();
        float2 za = make_float2(0.0f, 0.0f), zb = make_float2(0.0f, 0.0f);
        #pragma unroll
        for (int j = 0; j < 8; ++j) {
            const float4 v = bufF[64 * j + l];
            za.x = fmaf(E8f[j].x, v.x, za.x);  za.x = fmaf(-E8f[j].y, v.y, za.x);
            za.y = fmaf(E8f[j].x, v.y, za.y);  za.y = fmaf(E8f[j].y, v.x, za.y);
            zb.x = fmaf(E8f[j].x, v.z, zb.x);  zb.x = fmaf(-E8f[j].y, v.w, zb.x);
            zb.y = fmaf(E8f[j].x, v.w, zb.y);  zb.y = fmaf(E8f[j].y, v.z, zb.y);
        }
        z[0] = za; z[1] = zb;
        lane_fwd5(z);
    };

    // inv tail: lane 5 stages -> LDS radix-8 inverse gather -> radix-2, REAL only
    auto inv_tail = [&](float2 z[2], float& u0o, float& u1o) {
        lane_inv5(z);
        bufI[tt] = make_float4(z[0].x, z[0].y, z[1].x, z[1].y);
        __syncthreads();
        float vAx = 0.0f, vBx = 0.0f, vBy = 0.0f;
        #pragma unroll
        for (int j = 0; j < 8; ++j) {
            const float4 v = bufI[64 * j + l];
            vAx = fmaf(D8[j].x, v.x, vAx);  vAx = fmaf(-D8[j].y, v.y, vAx);
            vBx = fmaf(D8[j].x, v.z, vBx);  vBx = fmaf(-D8[j].y, v.w, vBx);
            vBy = fmaf(D8[j].x, v.w, vBy);  vBy = fmaf(D8[j].y, v.z, vBy);
        }
        const float re = vBx * T10.x + vBy * T10.y;   // Re(vB * conj(T10))
        u0o = vAx + re;
        u1o = vAx - re;
    };

    // ---- init: d_to_u (full unfused fwd + pointwise + full unfused inv) ----
    float2 z[2];
    float u0, u1;
    z[0] = make_float2(x[b * NFFT + tt], 0.0f);
    z[1] = make_float2(x[b * NFFT + tt + 512], 0.0f);
    fwd_head(z);
    #pragma unroll
    for (int r = 0; r < 2; ++r) fwd_s(z[r], qx1(z[r].x), qx1(z[r].y), 5);  // h=1
    #pragma unroll
    for (int p = 0; p < 2; ++p) {
        const float zx = z[p].x, zy = z[p].y;
        z[p] = make_float2(-zy * si[p], zx * si[p]);   // i*k*Z / N
    }
    { const bool m1 = (l & 1) != 0;
      #pragma unroll
      for (int r = 0; r < 2; ++r) inv_s(z[r], qx1(z[r].x), qx1(z[r].y), 0, m1); }
    inv_tail(z, u0, u1);

    for (int ot = 0; ot < nT; ++ot) {
        for (int ss = 0; ss < nsub; ++ss) {
            z[0] = make_float2(u0, 0.5f * u0 * u0);
            z[1] = make_float2(u1, 0.5f * u1 * u1);
            fwd_head(z);
            // fused: fwd h=1 + S scale + inv h=1 (real coefficients)
            #pragma unroll
            for (int p = 0; p < 2; ++p) {
                const float px = qx1(z[p].x), py = qx1(z[p].y);
                z[p].x = fmaf(A2[p], z[p].x, B2[p] * px);
                z[p].y = fmaf(A2[p], z[p].y, B2[p] * py);
            }
            inv_tail(z, u0, u1);
        }
        // snapshot: u_to_d (unfused)
        z[0] = make_float2(u0, 0.0f);
        z[1] = make_float2(u1, 0.0f);
        fwd_head(z);
        #pragma unroll
        for (int r = 0; r < 2; ++r) fwd_s(z[r], qx1(z[r].x), qx1(z[r].y), 5);
        #pragma unroll
        for (int p = 0; p < 2; ++p) {
            const float zx = z[p].x, zy = z[p].y;
            z[p] = make_float2(zy * csn[p], -zx * csn[p]);  // -i*Z/(N*k)
        }
        { const bool m1 = (l & 1) != 0;
          #pragma unroll
          for (int r = 0; r < 2; ++r) inv_s(z[r], qx1(z[r].x), qx1(z[r].y), 0, m1); }
        float d0, d1;
        inv_tail(z, d0, d1);
        out[(b * NFFT + tt) * nT + ot]       = d0;
        out[(b * NFFT + tt + 512) * nT + ot] = d1;
    }
}

extern "C" void kernel_launch(void* const* d_in, const int* in_sizes, int n_in,
                              void* d_out, int out_size, void* d_ws, size_t ws_size,
                              hipStream_t stream) {
    const float* x     = (const float*)d_in[0];
    const float* nu_p  = (const float*)d_in[1];
    const float* dto_p = (const float*)d_in[2];
    const float* cr_p  = (const float*)d_in[3];
    const int*   nt_p  = (const int*)d_in[4];
    const int*   ns_p  = (const int*)d_in[5];
    float* out = (float*)d_out;

    const int B = in_sizes[0] / NFFT;  // C == 1
    siva_kernel<<<B, BLK, 0, stream>>>(x, nu_p, dto_p, cr_p, nt_p, ns_p, out);
}